// Round 7
// baseline (2225.872 us; speedup 1.0000x reference)
//
#include <hip/hip_runtime.h>

#define NB 256
#define NT 256

typedef __attribute__((ext_vector_type(8))) short short8;
typedef __attribute__((ext_vector_type(4))) float f32x4;
typedef __attribute__((ext_vector_type(4))) unsigned u32x4;

constexpr int Bz = 64, Sz = 256, Tz = 32, Ez = 512, Hz = 512, G4 = 2048, VT = 32000;

__device__ __forceinline__ unsigned short f2b(float f) {
    unsigned u; __builtin_memcpy(&u, &f, 4);
    u = (u + 0x7fffu + ((u >> 16) & 1u)) >> 16;   // RNE fp32 -> bf16
    return (unsigned short)u;
}
__device__ __forceinline__ float sgm(float x) { return 1.0f / (1.0f + __expf(-x)); }
__device__ __forceinline__ float tnh(float x) { return 1.0f - 2.0f / (1.0f + __expf(2.0f * x)); }

// ===================== 0) workspace init =====================
// hq: [2 layer][2 parity][64 rows][128 quanta][16B] = 512 KB, all gens -> 0
__global__ __launch_bounds__(NT) void init_kernel(
    unsigned* __restrict__ hq, float* __restrict__ row_sums)
{
    const int idx = blockIdx.x * NT + threadIdx.x;     // 16384 threads x 8 u32 = 512KB
#pragma unroll
    for (int i = 0; i < 8; ++i) hq[idx * 8 + i] = 0u;
    if (blockIdx.x == 0 && threadIdx.x < 64) row_sums[threadIdx.x] = 0.0f;
}

// ===================== 1) LSTM scan — barrier-free, gen-validated exchange =====================
// Each 16B quantum = {data0(2 units), data1(2 units), gen, gen}: single dwordx4 store is
// naturally atomic -> freshness rides WITH the data. No drain, no arrive, no poll-detect.
// gen(step k) = k+1; init zeros = gen 0. Parity-2 reuse safety:
//  - L0/L1 peer overwrites: ordered by recurrence consume-before-produce (proof in session log).
//  - L0 overwriting h0(k-2) vs L1 readers: L0 verifies all 32 L1 markers gen>=k-1 before
//    storing (prefetched during staging; L1 can reach s=k-1 without L0's round-k store -> no cycle).
__global__ __launch_bounds__(NT, 2) void scan_kernel(
    const int* __restrict__ X, const int* __restrict__ Y,
    const float* __restrict__ emb_src, const float* __restrict__ emb_tgt,
    const float* __restrict__ eWih, const float* __restrict__ eWhh,
    const float* __restrict__ ebih, const float* __restrict__ ebhh,
    const float* __restrict__ dWih, const float* __restrict__ dWhh,
    const float* __restrict__ dbih, const float* __restrict__ dbhh,
    unsigned* __restrict__ hq)
{
    __shared__ __align__(16) unsigned char smem[39680];
    unsigned short* xh_lds = (unsigned short*)smem;          // [16][1024] bf16, 16B chunks XOR-swizzled by (row&7)
    float* gates_lds = (float*)(smem + 32768);               // [4][16][20] fp32
    float* c_lds     = (float*)(smem + 37888);               // [16][20] fp32, persists enc->dec
    unsigned* hstage = (unsigned*)(smem + 39168);            // [16][8] u32 h-packs

    const int tid  = threadIdx.x;
    const int bid  = blockIdx.x;
    const int lay  = bid >> 7;         // 0 or 1
    const int bt   = (bid >> 5) & 3;   // batch tile
    const int ht   = bid & 31;         // hidden-unit tile
    const int wave = tid >> 6;
    const int lane = tid & 63;
    const int nl   = lane & 15;
    const int quad = lane >> 4;

    for (int i = tid; i < 320; i += NT) c_lds[i] = 0.0f;
    __syncthreads();

    // ---- per-wave weight cache in VGPRs ----
    short8 wfrag[32];
    float bias_r = 0.0f;
    const int r = wave * 512 + ht * 16 + nl;

    auto load_w = [&](const float* Wih, const float* Whh,
                      const float* bih, const float* bhh) {
        const float* wi = Wih + (size_t)(lay * G4 + r) * 512;
        const float* wh = Whh + (size_t)(lay * G4 + r) * 512;
#pragma unroll
        for (int kc = 0; kc < 32; ++kc) {
            const int k0 = kc * 32 + quad * 8;
            const float* s = (k0 < 512) ? (wi + k0) : (wh + (k0 - 512));
            short8 v;
#pragma unroll
            for (int j = 0; j < 8; ++j) v[j] = (short)f2b(s[j]);
            wfrag[kc] = v;
        }
        bias_r = bih[lay * G4 + r] + bhh[lay * G4 + r];
    };

    const int kx = (nl >> 2) & 1;
    const int qx = quad ^ (nl & 3);

    // lane l covers LDS chunk l = units [8l,8l+8) = quanta {2l, 2l+1} (32B contiguous)
    auto lds_wr = [&](int rw, int half, u32x4 a, u32x4 b) {
        u32x4 d = {a.x, a.y, b.x, b.y};
        *(u32x4*)(xh_lds + (rw << 10) + (half ? 512 : 0) + ((lane ^ (rw & 7)) << 3)) = d;
    };

    // ---- L1 staging: x=h0(s) expects gen s+1; h=h1(s-1) expects gen s ----
    auto stage_l1 = [&](int s) {
        const int rb = wave << 2;
        const unsigned expx = (unsigned)(s + 1), exph = (unsigned)s;
        const unsigned* bx = hq + (size_t)(s & 1) * 32768;
        const unsigned* bh = hq + (size_t)(2 + ((s + 1) & 1)) * 32768;
        const unsigned* axp[4]; const unsigned* ahp[4];
#pragma unroll
        for (int rr = 0; rr < 4; ++rr) {
            const size_t g = (size_t)(bt * 16 + rb + rr);
            axp[rr] = bx + g * 512 + lane * 8;
            ahp[rr] = bh + g * 512 + lane * 8;
        }
        u32x4 xa[4], xb[4], ha[4], hb[4];
        bool okx = false, okh = false;
        for (;;) {
#pragma unroll
            for (int rr = 0; rr < 4; ++rr) {
                if (!okx)
                    asm volatile("global_load_dwordx4 %0, %2, off sc0 sc1\n\t"
                                 "global_load_dwordx4 %1, %2, off offset:16 sc0 sc1"
                                 : "=&v"(xa[rr]), "=&v"(xb[rr]) : "v"(axp[rr]) : "memory");
                if (!okh)
                    asm volatile("global_load_dwordx4 %0, %2, off sc0 sc1\n\t"
                                 "global_load_dwordx4 %1, %2, off offset:16 sc0 sc1"
                                 : "=&v"(ha[rr]), "=&v"(hb[rr]) : "v"(ahp[rr]) : "memory");
            }
            asm volatile("s_waitcnt vmcnt(0)"
                         : "+v"(xa[0]), "+v"(xb[0]), "+v"(xa[1]), "+v"(xb[1]),
                           "+v"(xa[2]), "+v"(xb[2]), "+v"(xa[3]), "+v"(xb[3]),
                           "+v"(ha[0]), "+v"(hb[0]), "+v"(ha[1]), "+v"(hb[1]),
                           "+v"(ha[2]), "+v"(hb[2]), "+v"(ha[3]), "+v"(hb[3]) :: "memory");
            __builtin_amdgcn_sched_barrier(0);
            bool px = true, ph = true;
#pragma unroll
            for (int rr = 0; rr < 4; ++rr) {
                px = px && (xa[rr].z == expx) && (xb[rr].z == expx);
                ph = ph && (ha[rr].z == exph) && (hb[rr].z == exph);
            }
            okx = okx || __all((int)px);
            okh = okh || __all((int)ph);
            if (okx && okh) break;
            __builtin_amdgcn_s_sleep(1);
        }
#pragma unroll
        for (int rr = 0; rr < 4; ++rr) {
            lds_wr(rb + rr, 0, xa[rr], xb[rr]);
            lds_wr(rb + rr, 1, ha[rr], hb[rr]);
        }
    };

    // ---- L0 staging: h0(k-1) expects gen k; x from embedding (static). Marker prefetch. ----
    auto stage_l0 = [&](int k, const float* xtab, const int* tok, int stride, int col,
                        int bos, unsigned& mg) {
        const int rb = wave << 2;
        const unsigned exph = (unsigned)k;
        const unsigned* bh = hq + (size_t)((k + 1) & 1) * 32768;
        const unsigned* ahp[4];
#pragma unroll
        for (int rr = 0; rr < 4; ++rr)
            ahp[rr] = bh + (size_t)(bt * 16 + rb + rr) * 512 + lane * 8;
        u32x4 ha[4], hb[4];
#pragma unroll
        for (int rr = 0; rr < 4; ++rr)
            asm volatile("global_load_dwordx4 %0, %2, off sc0 sc1\n\t"
                         "global_load_dwordx4 %1, %2, off offset:16 sc0 sc1"
                         : "=&v"(ha[rr]), "=&v"(hb[rr]) : "v"(ahp[rr]) : "memory");
        if (wave == 0 && lane < 32 && k >= 2)   // prefetch L1 progress markers
            mg = __hip_atomic_load(hq + (size_t)(2 + (k & 1)) * 32768 +
                                   (size_t)(bt * 16) * 512 + (size_t)lane * 16 + 2,
                                   __ATOMIC_RELAXED, __HIP_MEMORY_SCOPE_AGENT);
        {   // embedding x-half (overlaps the h flight)
            int tk[4];
#pragma unroll
            for (int rr = 0; rr < 4; ++rr)
                tk[rr] = bos ? 2 : tok[(bt * 16 + rb + rr) * stride + col];
#pragma unroll
            for (int rr = 0; rr < 4; ++rr) {
                const int rw = rb + rr;
                const float* s = xtab + (size_t)tk[rr] * Ez + (lane << 3);
                float4 lo = *(const float4*)s;
                float4 hi = *(const float4*)(s + 4);
                short8 v;
                v[0] = (short)f2b(lo.x); v[1] = (short)f2b(lo.y);
                v[2] = (short)f2b(lo.z); v[3] = (short)f2b(lo.w);
                v[4] = (short)f2b(hi.x); v[5] = (short)f2b(hi.y);
                v[6] = (short)f2b(hi.z); v[7] = (short)f2b(hi.w);
                *(short8*)(xh_lds + (rw << 10) + ((lane ^ (rw & 7)) << 3)) = v;
            }
        }
        for (;;) {
            asm volatile("s_waitcnt vmcnt(0)"
                         : "+v"(ha[0]), "+v"(hb[0]), "+v"(ha[1]), "+v"(hb[1]),
                           "+v"(ha[2]), "+v"(hb[2]), "+v"(ha[3]), "+v"(hb[3]) :: "memory");
            __builtin_amdgcn_sched_barrier(0);
            bool ok = true;
#pragma unroll
            for (int rr = 0; rr < 4; ++rr)
                ok = ok && (ha[rr].z == exph) && (hb[rr].z == exph);
            if (__all((int)ok)) break;
            __builtin_amdgcn_s_sleep(1);
#pragma unroll
            for (int rr = 0; rr < 4; ++rr)
                asm volatile("global_load_dwordx4 %0, %2, off sc0 sc1\n\t"
                             "global_load_dwordx4 %1, %2, off offset:16 sc0 sc1"
                             : "=&v"(ha[rr]), "=&v"(hb[rr]) : "v"(ahp[rr]) : "memory");
        }
#pragma unroll
        for (int rr = 0; rr < 4; ++rr) lds_wr(rb + rr, 1, ha[rr], hb[rr]);
    };

    // ---- MFMA + activations + c/h update -> hstage packs ----
    auto mfma_core = [&]() {
        const unsigned short* arE = xh_lds + (nl << 10) + (qx << 3) + (kx << 5);
        const unsigned short* arO = xh_lds + (nl << 10) + (qx << 3) - (kx << 5);
        f32x4 a0 = {0.f, 0.f, 0.f, 0.f}, a1 = a0, a2 = a0, a3 = a0;
#pragma unroll
        for (int kc = 0; kc < 32; kc += 4) {
            short8 x0 = *(const short8*)(arE + ((kc + 0) << 5));
            short8 x1 = *(const short8*)(arO + ((kc + 1) << 5));
            short8 x2 = *(const short8*)(arE + ((kc + 2) << 5));
            short8 x3 = *(const short8*)(arO + ((kc + 3) << 5));
            a0 = __builtin_amdgcn_mfma_f32_16x16x32_bf16(x0, wfrag[kc + 0], a0, 0, 0, 0);
            a1 = __builtin_amdgcn_mfma_f32_16x16x32_bf16(x1, wfrag[kc + 1], a1, 0, 0, 0);
            a2 = __builtin_amdgcn_mfma_f32_16x16x32_bf16(x2, wfrag[kc + 2], a2, 0, 0, 0);
            a3 = __builtin_amdgcn_mfma_f32_16x16x32_bf16(x3, wfrag[kc + 3], a3, 0, 0, 0);
        }
        f32x4 acc = (a0 + a1) + (a2 + a3);
#pragma unroll
        for (int i = 0; i < 4; ++i) {
            float v = acc[i] + bias_r;
            v = (wave == 2) ? tnh(v) : sgm(v);
            gates_lds[wave * 320 + (quad * 4 + i) * 20 + nl] = v;
        }
        __syncthreads();
        if (tid < 128) {
            const int m = tid >> 3, np = tid & 7;
            float hp[2];
#pragma unroll
            for (int j = 0; j < 2; ++j) {
                const int n = 2 * np + j;
                const float iv = gates_lds[      m * 20 + n];
                const float fv = gates_lds[320 + m * 20 + n];
                const float gv = gates_lds[640 + m * 20 + n];
                const float ov = gates_lds[960 + m * 20 + n];
                float c = c_lds[m * 20 + n];
                c = fv * c + iv * gv;
                c_lds[m * 20 + n] = c;
                hp[j] = ov * tnh(c);
            }
            hstage[m * 8 + np] = (unsigned)f2b(hp[0]) | ((unsigned)f2b(hp[1]) << 16);
        }
    };

    // ---- quantum store: wave0, 64x16B, fire-and-forget (gen rides in the store) ----
    auto store_h = [&](int k, unsigned& mg, bool need_marker) {
        if (tid < 64) {
            if (need_marker) {
                const unsigned* mp = hq + (size_t)(2 + (k & 1)) * 32768 +
                                     (size_t)(bt * 16) * 512 + (size_t)lane * 16 + 2;
                const unsigned kk = (unsigned)(k - 1);
                while (!__all((int)((lane >= 32) || (mg >= kk)))) {
                    __builtin_amdgcn_s_sleep(1);
                    if (lane < 32)
                        mg = __hip_atomic_load(mp, __ATOMIC_RELAXED, __HIP_MEMORY_SCOPE_AGENT);
                }
            }
            const int m = tid >> 2, qi = tid & 3;
            const unsigned d0 = hstage[m * 8 + 2 * qi], d1 = hstage[m * 8 + 2 * qi + 1];
            u32x4 qv = {d0, d1, (unsigned)(k + 1), (unsigned)(k + 1)};
            unsigned* dst = hq + (size_t)(lay * 2 + (k & 1)) * 32768 +
                            (size_t)(bt * 16 + m) * 512 + (size_t)(ht * 4 + qi) * 4;
            asm volatile("global_store_dwordx4 %0, %1, off sc0 sc1"
                         :: "v"(dst), "v"(qv) : "memory");
        }
    };

    if (lay == 0) {
        load_w(eWih, eWhh, ebih, ebhh);
        unsigned mg = 0;
        for (int k = 0; k < Sz + Tz; ++k) {
            if (k == Sz) load_w(dWih, dWhh, dbih, dbhh);
            const float* xtab; const int* tok; int stride, col, bos;
            if (k < Sz) { xtab = emb_src; tok = X; stride = Sz; col = k; bos = 0; }
            else { const int kd = k - Sz; xtab = emb_tgt; tok = Y; stride = Tz;
                   col = kd ? kd - 1 : 0; bos = (kd == 0); }
            stage_l0(k, xtab, tok, stride, col, bos, mg);
            __syncthreads();
            mfma_core();
            __syncthreads();
            store_h(k, mg, k >= 2);
        }
    } else {
        load_w(eWih, eWhh, ebih, ebhh);
        unsigned dummy = 0;
        for (int s = 0; s < Sz + Tz; ++s) {
            if (s == Sz) load_w(dWih, dWhh, dbih, dbhh);
            stage_l1(s);
            __syncthreads();
            mfma_core();
            __syncthreads();
            store_h(s, dummy, false);
        }
    }
    // L1 final h1 sits in hq layer1 parity ((Sz+Tz-1)&1)=1; FC reads it (kernel boundary).
}

// ===================== 2) FC [64 x 32000] + exp-sum =====================
__global__ __launch_bounds__(NT, 1) void fc_kernel(
    const float* __restrict__ fcW, const float* __restrict__ fcb,
    const unsigned* __restrict__ hq,
    float* __restrict__ logits, float* __restrict__ row_sums)
{
    __shared__ __align__(16) unsigned char smem[66816];
    unsigned short* h_lds = (unsigned short*)smem;          // [64][520] bf16
    float* row_part = (float*)(smem + 64 * 520 * 2);        // [64]

    const int tid  = threadIdx.x;
    const int bid  = blockIdx.x;
    const int wave = tid >> 6;
    const int lane = tid & 63;
    const int nl   = lane & 15;
    const int quad = lane >> 4;

    {   // stage top hidden from quanta: layer1 parity1 base = 3*32768 u32
        const int rr2 = tid >> 2, pp = tid & 3;
        const unsigned* hrow = hq + (size_t)(3 * 64 + 0) * 512 + (size_t)rr2 * 512 + pp * 128;
#pragma unroll
        for (int i = 0; i < 16; ++i) {
            u32x4 q0 = *(const u32x4*)(hrow + i * 8);
            u32x4 q1 = *(const u32x4*)(hrow + i * 8 + 4);
            u32x4 d = {q0.x, q0.y, q1.x, q1.y};
            *(u32x4*)(h_lds + rr2 * 520 + pp * 128 + i * 8) = d;
        }
    }
    if (tid < 64) row_part[tid] = 0.f;
    __syncthreads();

    const int c0 = bid * 128;
    f32x4 acc[8];
#pragma unroll
    for (int ct = 0; ct < 8; ++ct) acc[ct] = (f32x4){0.f, 0.f, 0.f, 0.f};
    const unsigned short* ar = h_lds + (wave * 16 + nl) * 520 + quad * 8;
    const float* bb = fcW + ((size_t)c0 + nl) * 512 + quad * 8;
    for (int kc = 0; kc < 16; ++kc) {
        short8 a = *(const short8*)(ar + kc * 32);
#pragma unroll
        for (int ct = 0; ct < 8; ++ct) {
            const float* bp = bb + (size_t)ct * 16 * 512 + kc * 32;
            float4 lo = *(const float4*)(bp);
            float4 hi = *(const float4*)(bp + 4);
            short8 b;
            b[0] = (short)f2b(lo.x); b[1] = (short)f2b(lo.y);
            b[2] = (short)f2b(lo.z); b[3] = (short)f2b(lo.w);
            b[4] = (short)f2b(hi.x); b[5] = (short)f2b(hi.y);
            b[6] = (short)f2b(hi.z); b[7] = (short)f2b(hi.w);
            acc[ct] = __builtin_amdgcn_mfma_f32_16x16x32_bf16(a, b, acc[ct], 0, 0, 0);
        }
    }
    float ls[4] = {0.f, 0.f, 0.f, 0.f};
#pragma unroll
    for (int ct = 0; ct < 8; ++ct) {
        const int col = c0 + ct * 16 + nl;
        const float bias = fcb[col];
#pragma unroll
        for (int i = 0; i < 4; ++i) {
            const float lg = acc[ct][i] + bias;
            logits[(size_t)(wave * 16 + quad * 4 + i) * VT + col] = lg;
            ls[i] += __expf(lg);
        }
    }
#pragma unroll
    for (int i = 0; i < 4; ++i)
        atomicAdd(&row_part[wave * 16 + quad * 4 + i], ls[i]);
    __syncthreads();
    if (tid < 64) atomicAdd(&row_sums[tid], row_part[tid]);
}

// ===================== 3) normalize =====================
__global__ __launch_bounds__(NT) void norm_kernel(
    const float* __restrict__ logits, const float* __restrict__ row_sums,
    float* __restrict__ out)
{
    const int idx = blockIdx.x * NT + threadIdx.x;
    const int row = idx / VT;
    out[idx] = logits[idx] - __logf(row_sums[row]);
}

extern "C" void kernel_launch(void* const* d_in, const int* in_sizes, int n_in,
                              void* d_out, int out_size, void* d_ws, size_t ws_size,
                              hipStream_t stream) {
    const int* X = (const int*)d_in[0];
    const int* Y = (const int*)d_in[1];
    const float* emb_src = (const float*)d_in[2];
    const float* emb_tgt = (const float*)d_in[3];
    const float* eWih = (const float*)d_in[4];
    const float* eWhh = (const float*)d_in[5];
    const float* ebih = (const float*)d_in[6];
    const float* ebhh = (const float*)d_in[7];
    const float* dWih = (const float*)d_in[8];
    const float* dWhh = (const float*)d_in[9];
    const float* dbih = (const float*)d_in[10];
    const float* dbhh = (const float*)d_in[11];
    const float* fcW = (const float*)d_in[12];
    const float* fcb = (const float*)d_in[13];
    float* out = (float*)d_out;

    // ws layout: [0,512KB) gen-quanta h buffers; [512KB,+256B) row_sums;
    //            [520KB, +8.192MB) fp32 logits
    unsigned* hq    = (unsigned*)d_ws;
    float* row_sums = (float*)((char*)d_ws + 524288);
    float* logits   = (float*)((char*)d_ws + 532480);

    init_kernel<<<dim3(64), dim3(NT), 0, stream>>>(hq, row_sums);

    void* args[] = {&X, &Y, &emb_src, &emb_tgt, &eWih, &eWhh, &ebih, &ebhh,
                    &dWih, &dWhh, &dbih, &dbhh, &hq};
    hipLaunchCooperativeKernel(reinterpret_cast<void*>(scan_kernel),
                               dim3(NB), dim3(NT), args, 0, stream);

    fc_kernel<<<dim3(VT / 128), dim3(NT), 0, stream>>>(fcW, fcb, hq, logits, row_sums);

    norm_kernel<<<dim3((Bz * VT) / NT), dim3(NT), 0, stream>>>(logits, row_sums, out);
}

// Round 8
// 2147.187 us; speedup vs baseline: 1.0366x; 1.0366x over previous
//
#include <hip/hip_runtime.h>

#define NB 256
#define NT 256

typedef __attribute__((ext_vector_type(8))) short short8;
typedef __attribute__((ext_vector_type(4))) float f32x4;
typedef __attribute__((ext_vector_type(4))) unsigned u32x4;

constexpr int Bz = 64, Sz = 256, Tz = 32, Ez = 512, Hz = 512, G4 = 2048, VT = 32000;

__device__ __forceinline__ unsigned short f2b(float f) {
    unsigned u; __builtin_memcpy(&u, &f, 4);
    u = (u + 0x7fffu + ((u >> 16) & 1u)) >> 16;   // RNE fp32 -> bf16
    return (unsigned short)u;
}
__device__ __forceinline__ float sgm(float x) { return 1.0f / (1.0f + __expf(-x)); }
__device__ __forceinline__ float tnh(float x) { return 1.0f - 2.0f / (1.0f + __expf(2.0f * x)); }
__device__ __forceinline__ unsigned umin2(unsigned a, unsigned b) { return a < b ? a : b; }
__device__ __forceinline__ unsigned min4u(u32x4 v) {
    return umin2(umin2(v.x, v.y), umin2(v.z, v.w));
}

// ===================== 0) workspace init =====================
// hq: [2 layer][2 parity][64 rows][128 quanta{d0,d1,gen,gen}] = 512 KB, gens -> 0
__global__ __launch_bounds__(NT) void init_kernel(
    unsigned* __restrict__ hq, float* __restrict__ row_sums,
    unsigned* __restrict__ bars)
{
    const int idx = blockIdx.x * NT + threadIdx.x;     // 16384 threads x 8 u32 = 512KB
#pragma unroll
    for (int i = 0; i < 8; ++i) hq[idx * 8 + i] = 0u;
    if (blockIdx.x == 0) {
        bars[threadIdx.x] = 0u;                        // [4 groups][64 u32] arrival slots
        if (threadIdx.x < 64) row_sums[threadIdx.x] = 0.0f;
    }
}

// ===================== 1) LSTM scan =====================
// Exchange: 16B quanta {data0, data1, gen, gen} — naturally-atomic dwordx4 stores carry
// freshness WITH the data, so producers need NO vmcnt drain before signaling.
// Throttle: round-6 proven slot barrier (per-block slot store + tid0 min-poll of 256B).
// Post-detect loads validate embedded gens (correctness net; ~never retries since data
// stores were issued ~1.5 LLC-RTTs before the consumer's load returns).
__global__ __launch_bounds__(NT, 2) void scan_kernel(
    const int* __restrict__ X, const int* __restrict__ Y,
    const float* __restrict__ emb_src, const float* __restrict__ emb_tgt,
    const float* __restrict__ eWih, const float* __restrict__ eWhh,
    const float* __restrict__ ebih, const float* __restrict__ ebhh,
    const float* __restrict__ dWih, const float* __restrict__ dWhh,
    const float* __restrict__ dbih, const float* __restrict__ dbhh,
    unsigned* __restrict__ hq, unsigned* __restrict__ bars)
{
    __shared__ __align__(16) unsigned char smem[39680];
    unsigned short* xh_lds = (unsigned short*)smem;          // [16][1024] bf16, chunk-XOR-swizzled
    float* gates_lds = (float*)(smem + 32768);               // [4][16][20] fp32
    float* c_lds     = (float*)(smem + 37888);               // [16][20] fp32, persists enc->dec
    unsigned* hstage = (unsigned*)(smem + 39168);            // [16][8] u32 h-packs

    const int tid  = threadIdx.x;
    const int bid  = blockIdx.x;
    const int lay  = bid >> 7;         // 0 or 1
    const int bt   = (bid >> 5) & 3;   // batch tile
    const int ht   = bid & 31;         // hidden-unit tile
    const int wave = tid >> 6;
    const int lane = tid & 63;
    const int nl   = lane & 15;
    const int quad = lane >> 4;

    unsigned* slots = bars + bt * 64;
    const int myslot = lay * 32 + ht;
    unsigned gen = 0;

    // signal + throttle: NO data drain — slot store issues right after data stores
    // (same wave, program order); gen-validation on the consumer side nets any skew.
    auto barrier_sig = [&]() {
        ++gen;
        if (tid == 0) {
            __hip_atomic_store(slots + myslot, gen,
                               __ATOMIC_RELAXED, __HIP_MEMORY_SCOPE_AGENT);
            for (;;) {
                u32x4 a, b, c, d;
                asm volatile(
                    "global_load_dwordx4 %0, %4, off sc0 sc1\n\t"
                    "global_load_dwordx4 %1, %4, off offset:16 sc0 sc1\n\t"
                    "global_load_dwordx4 %2, %4, off offset:32 sc0 sc1\n\t"
                    "global_load_dwordx4 %3, %4, off offset:48 sc0 sc1\n\t"
                    "s_waitcnt vmcnt(0)"
                    : "=&v"(a), "=&v"(b), "=&v"(c), "=&v"(d)
                    : "v"(slots)
                    : "memory");
                const unsigned m = umin2(umin2(min4u(a), min4u(b)),
                                         umin2(min4u(c), min4u(d)));
                if (m >= gen) break;
            }
        }
        __syncthreads();
    };

    for (int i = tid; i < 320; i += NT) c_lds[i] = 0.0f;
    __syncthreads();

    // ---- per-wave weight cache in VGPRs ----
    short8 wfrag[32];
    float bias_r = 0.0f;
    const int r = wave * 512 + ht * 16 + nl;

    auto load_w = [&](const float* Wih, const float* Whh,
                      const float* bih, const float* bhh) {
        const float* wi = Wih + (size_t)(lay * G4 + r) * 512;
        const float* wh = Whh + (size_t)(lay * G4 + r) * 512;
#pragma unroll
        for (int kc = 0; kc < 32; ++kc) {
            const int k0 = kc * 32 + quad * 8;
            const float* s = (k0 < 512) ? (wi + k0) : (wh + (k0 - 512));
            short8 v;
#pragma unroll
            for (int j = 0; j < 8; ++j) v[j] = (short)f2b(s[j]);
            wfrag[kc] = v;
        }
        bias_r = bih[lay * G4 + r] + bhh[lay * G4 + r];
    };

    const int kx = (nl >> 2) & 1;
    const int qx = quad ^ (nl & 3);

    // lane l covers LDS chunk l = units [8l,8l+8) = quanta {2l, 2l+1}
    auto lds_wr = [&](int rw, int half, u32x4 a, u32x4 b) {
        u32x4 d = {a.x, a.y, b.x, b.y};
        *(u32x4*)(xh_lds + (rw << 10) + (half ? 512 : 0) + ((lane ^ (rw & 7)) << 3)) = d;
    };

    // ---- L1 staging: x=h0(s) expects gen s+1; h=h1(s-1) expects gen s ----
    auto stage_l1 = [&](int s) {
        const int rb = wave << 2;
        const unsigned expx = (unsigned)(s + 1), exph = (unsigned)s;
        const unsigned* bx = hq + (size_t)(s & 1) * 32768;
        const unsigned* bh = hq + (size_t)(2 + ((s + 1) & 1)) * 32768;
        const unsigned* axp[4]; const unsigned* ahp[4];
#pragma unroll
        for (int rr = 0; rr < 4; ++rr) {
            const size_t g = (size_t)(bt * 16 + rb + rr);
            axp[rr] = bx + g * 512 + lane * 8;
            ahp[rr] = bh + g * 512 + lane * 8;
        }
        u32x4 xa[4], xb[4], ha[4], hb[4];
        bool okx = false, okh = false;
        for (;;) {
#pragma unroll
            for (int rr = 0; rr < 4; ++rr) {
                if (!okx)
                    asm volatile("global_load_dwordx4 %0, %2, off sc0 sc1\n\t"
                                 "global_load_dwordx4 %1, %2, off offset:16 sc0 sc1"
                                 : "=&v"(xa[rr]), "=&v"(xb[rr]) : "v"(axp[rr]) : "memory");
                if (!okh)
                    asm volatile("global_load_dwordx4 %0, %2, off sc0 sc1\n\t"
                                 "global_load_dwordx4 %1, %2, off offset:16 sc0 sc1"
                                 : "=&v"(ha[rr]), "=&v"(hb[rr]) : "v"(ahp[rr]) : "memory");
            }
            asm volatile("s_waitcnt vmcnt(0)"
                         : "+v"(xa[0]), "+v"(xb[0]), "+v"(xa[1]), "+v"(xb[1]),
                           "+v"(xa[2]), "+v"(xb[2]), "+v"(xa[3]), "+v"(xb[3]),
                           "+v"(ha[0]), "+v"(hb[0]), "+v"(ha[1]), "+v"(hb[1]),
                           "+v"(ha[2]), "+v"(hb[2]), "+v"(ha[3]), "+v"(hb[3]) :: "memory");
            __builtin_amdgcn_sched_barrier(0);
            bool px = true, ph = true;
#pragma unroll
            for (int rr = 0; rr < 4; ++rr) {
                px = px && (xa[rr].z == expx) && (xb[rr].z == expx);
                ph = ph && (ha[rr].z == exph) && (hb[rr].z == exph);
            }
            okx = okx || __all((int)px);
            okh = okh || __all((int)ph);
            if (okx && okh) break;
            __builtin_amdgcn_s_sleep(1);
        }
#pragma unroll
        for (int rr = 0; rr < 4; ++rr) {
            lds_wr(rb + rr, 0, xa[rr], xb[rr]);
            lds_wr(rb + rr, 1, ha[rr], hb[rr]);
        }
    };

    // ---- L0 staging: h0(k-1) expects gen k; x from embedding (static) ----
    auto stage_l0 = [&](int k, const float* xtab, const int* tok, int stride, int col,
                        int bos) {
        const int rb = wave << 2;
        const unsigned exph = (unsigned)k;
        const unsigned* bh = hq + (size_t)((k + 1) & 1) * 32768;
        const unsigned* ahp[4];
#pragma unroll
        for (int rr = 0; rr < 4; ++rr)
            ahp[rr] = bh + (size_t)(bt * 16 + rb + rr) * 512 + lane * 8;
        u32x4 ha[4], hb[4];
#pragma unroll
        for (int rr = 0; rr < 4; ++rr)
            asm volatile("global_load_dwordx4 %0, %2, off sc0 sc1\n\t"
                         "global_load_dwordx4 %1, %2, off offset:16 sc0 sc1"
                         : "=&v"(ha[rr]), "=&v"(hb[rr]) : "v"(ahp[rr]) : "memory");
        {   // embedding x-half (overlaps the h flight)
            int tk[4];
#pragma unroll
            for (int rr = 0; rr < 4; ++rr)
                tk[rr] = bos ? 2 : tok[(bt * 16 + rb + rr) * stride + col];
#pragma unroll
            for (int rr = 0; rr < 4; ++rr) {
                const int rw = rb + rr;
                const float* s = xtab + (size_t)tk[rr] * Ez + (lane << 3);
                float4 lo = *(const float4*)s;
                float4 hi = *(const float4*)(s + 4);
                short8 v;
                v[0] = (short)f2b(lo.x); v[1] = (short)f2b(lo.y);
                v[2] = (short)f2b(lo.z); v[3] = (short)f2b(lo.w);
                v[4] = (short)f2b(hi.x); v[5] = (short)f2b(hi.y);
                v[6] = (short)f2b(hi.z); v[7] = (short)f2b(hi.w);
                *(short8*)(xh_lds + (rw << 10) + ((lane ^ (rw & 7)) << 3)) = v;
            }
        }
        for (;;) {
            asm volatile("s_waitcnt vmcnt(0)"
                         : "+v"(ha[0]), "+v"(hb[0]), "+v"(ha[1]), "+v"(hb[1]),
                           "+v"(ha[2]), "+v"(hb[2]), "+v"(ha[3]), "+v"(hb[3]) :: "memory");
            __builtin_amdgcn_sched_barrier(0);
            bool ok = true;
#pragma unroll
            for (int rr = 0; rr < 4; ++rr)
                ok = ok && (ha[rr].z == exph) && (hb[rr].z == exph);
            if (__all((int)ok)) break;
            __builtin_amdgcn_s_sleep(1);
#pragma unroll
            for (int rr = 0; rr < 4; ++rr)
                asm volatile("global_load_dwordx4 %0, %2, off sc0 sc1\n\t"
                             "global_load_dwordx4 %1, %2, off offset:16 sc0 sc1"
                             : "=&v"(ha[rr]), "=&v"(hb[rr]) : "v"(ahp[rr]) : "memory");
        }
#pragma unroll
        for (int rr = 0; rr < 4; ++rr) lds_wr(rb + rr, 1, ha[rr], hb[rr]);
    };

    // ---- MFMA + activations + c/h update -> hstage packs ----
    auto mfma_core = [&]() {
        const unsigned short* arE = xh_lds + (nl << 10) + (qx << 3) + (kx << 5);
        const unsigned short* arO = xh_lds + (nl << 10) + (qx << 3) - (kx << 5);
        f32x4 a0 = {0.f, 0.f, 0.f, 0.f}, a1 = a0, a2 = a0, a3 = a0;
#pragma unroll
        for (int kc = 0; kc < 32; kc += 4) {
            short8 x0 = *(const short8*)(arE + ((kc + 0) << 5));
            short8 x1 = *(const short8*)(arO + ((kc + 1) << 5));
            short8 x2 = *(const short8*)(arE + ((kc + 2) << 5));
            short8 x3 = *(const short8*)(arO + ((kc + 3) << 5));
            a0 = __builtin_amdgcn_mfma_f32_16x16x32_bf16(x0, wfrag[kc + 0], a0, 0, 0, 0);
            a1 = __builtin_amdgcn_mfma_f32_16x16x32_bf16(x1, wfrag[kc + 1], a1, 0, 0, 0);
            a2 = __builtin_amdgcn_mfma_f32_16x16x32_bf16(x2, wfrag[kc + 2], a2, 0, 0, 0);
            a3 = __builtin_amdgcn_mfma_f32_16x16x32_bf16(x3, wfrag[kc + 3], a3, 0, 0, 0);
        }
        f32x4 acc = (a0 + a1) + (a2 + a3);
#pragma unroll
        for (int i = 0; i < 4; ++i) {
            float v = acc[i] + bias_r;
            v = (wave == 2) ? tnh(v) : sgm(v);
            gates_lds[wave * 320 + (quad * 4 + i) * 20 + nl] = v;
        }
        __syncthreads();
        if (tid < 128) {
            const int m = tid >> 3, np = tid & 7;
            float hp[2];
#pragma unroll
            for (int j = 0; j < 2; ++j) {
                const int n = 2 * np + j;
                const float iv = gates_lds[      m * 20 + n];
                const float fv = gates_lds[320 + m * 20 + n];
                const float gv = gates_lds[640 + m * 20 + n];
                const float ov = gates_lds[960 + m * 20 + n];
                float c = c_lds[m * 20 + n];
                c = fv * c + iv * gv;
                c_lds[m * 20 + n] = c;
                hp[j] = ov * tnh(c);
            }
            hstage[m * 8 + np] = (unsigned)f2b(hp[0]) | ((unsigned)f2b(hp[1]) << 16);
        }
    };

    // ---- quantum store: wave0, 64x16B, fire-and-forget (gen rides in the store) ----
    auto store_h = [&](int k) {
        if (tid < 64) {
            const int m = tid >> 2, qi = tid & 3;
            const unsigned d0 = hstage[m * 8 + 2 * qi], d1 = hstage[m * 8 + 2 * qi + 1];
            u32x4 qv = {d0, d1, (unsigned)(k + 1), (unsigned)(k + 1)};
            unsigned* dst = hq + (size_t)(lay * 2 + (k & 1)) * 32768 +
                            (size_t)(bt * 16 + m) * 512 + (size_t)(ht * 4 + qi) * 4;
            asm volatile("global_store_dwordx4 %0, %1, off sc0 sc1"
                         :: "v"(dst), "v"(qv) : "memory");
        }
    };

    if (lay == 0) {
        load_w(eWih, eWhh, ebih, ebhh);
        for (int k = 0; k < Sz + Tz; ++k) {          // rounds 0..287
            if (k == Sz) load_w(dWih, dWhh, dbih, dbhh);
            const float* xtab; const int* tok; int stride, col, bos;
            if (k < Sz) { xtab = emb_src; tok = X; stride = Sz; col = k; bos = 0; }
            else { const int kd = k - Sz; xtab = emb_tgt; tok = Y; stride = Tz;
                   col = kd ? kd - 1 : 0; bos = (kd == 0); }
            stage_l0(k, xtab, tok, stride, col, bos);
            __syncthreads();
            mfma_core();
            __syncthreads();                          // hstage visible to wave0
            store_h(k);
            barrier_sig();
        }
    } else {
        load_w(eWih, eWhh, ebih, ebhh);
        barrier_sig();                                // round 0: no work, join barrier
        for (int s = 0; s < Sz + Tz; ++s) {          // rounds 1..288
            if (s == Sz) load_w(dWih, dWhh, dbih, dbhh);
            stage_l1(s);
            __syncthreads();
            mfma_core();
            __syncthreads();
            store_h(s);
            if (s < Sz + Tz - 1) barrier_sig();       // last round: kernel boundary syncs
        }
    }
    // L1 final h1 sits in hq layer1 parity1; FC reads it (kernel-boundary sync).
}

// ===================== 2) FC [64 x 32000] + exp-sum =====================
__global__ __launch_bounds__(NT, 1) void fc_kernel(
    const float* __restrict__ fcW, const float* __restrict__ fcb,
    const unsigned* __restrict__ hq,
    float* __restrict__ logits, float* __restrict__ row_sums)
{
    __shared__ __align__(16) unsigned char smem[66816];
    unsigned short* h_lds = (unsigned short*)smem;          // [64][520] bf16
    float* row_part = (float*)(smem + 64 * 520 * 2);        // [64]

    const int tid  = threadIdx.x;
    const int bid  = blockIdx.x;
    const int wave = tid >> 6;
    const int lane = tid & 63;
    const int nl   = lane & 15;
    const int quad = lane >> 4;

    {   // stage top hidden from quanta: layer1 parity1 base = 3*32768 u32
        const int rr2 = tid >> 2, pp = tid & 3;
        const unsigned* hrow = hq + (size_t)3 * 32768 + (size_t)rr2 * 512 + pp * 128;
#pragma unroll
        for (int i = 0; i < 16; ++i) {
            u32x4 q0 = *(const u32x4*)(hrow + i * 8);
            u32x4 q1 = *(const u32x4*)(hrow + i * 8 + 4);
            u32x4 d = {q0.x, q0.y, q1.x, q1.y};
            *(u32x4*)(h_lds + rr2 * 520 + pp * 128 + i * 8) = d;
        }
    }
    if (tid < 64) row_part[tid] = 0.f;
    __syncthreads();

    const int c0 = bid * 128;
    f32x4 acc[8];
#pragma unroll
    for (int ct = 0; ct < 8; ++ct) acc[ct] = (f32x4){0.f, 0.f, 0.f, 0.f};
    const unsigned short* ar = h_lds + (wave * 16 + nl) * 520 + quad * 8;
    const float* bb = fcW + ((size_t)c0 + nl) * 512 + quad * 8;
    for (int kc = 0; kc < 16; ++kc) {
        short8 a = *(const short8*)(ar + kc * 32);
#pragma unroll
        for (int ct = 0; ct < 8; ++ct) {
            const float* bp = bb + (size_t)ct * 16 * 512 + kc * 32;
            float4 lo = *(const float4*)(bp);
            float4 hi = *(const float4*)(bp + 4);
            short8 b;
            b[0] = (short)f2b(lo.x); b[1] = (short)f2b(lo.y);
            b[2] = (short)f2b(lo.z); b[3] = (short)f2b(lo.w);
            b[4] = (short)f2b(hi.x); b[5] = (short)f2b(hi.y);
            b[6] = (short)f2b(hi.z); b[7] = (short)f2b(hi.w);
            acc[ct] = __builtin_amdgcn_mfma_f32_16x16x32_bf16(a, b, acc[ct], 0, 0, 0);
        }
    }
    float ls[4] = {0.f, 0.f, 0.f, 0.f};
#pragma unroll
    for (int ct = 0; ct < 8; ++ct) {
        const int col = c0 + ct * 16 + nl;
        const float bias = fcb[col];
#pragma unroll
        for (int i = 0; i < 4; ++i) {
            const float lg = acc[ct][i] + bias;
            logits[(size_t)(wave * 16 + quad * 4 + i) * VT + col] = lg;
            ls[i] += __expf(lg);
        }
    }
#pragma unroll
    for (int i = 0; i < 4; ++i)
        atomicAdd(&row_part[wave * 16 + quad * 4 + i], ls[i]);
    __syncthreads();
    if (tid < 64) atomicAdd(&row_sums[tid], row_part[tid]);
}

// ===================== 3) normalize =====================
__global__ __launch_bounds__(NT) void norm_kernel(
    const float* __restrict__ logits, const float* __restrict__ row_sums,
    float* __restrict__ out)
{
    const int idx = blockIdx.x * NT + threadIdx.x;
    const int row = idx / VT;
    out[idx] = logits[idx] - __logf(row_sums[row]);
}

extern "C" void kernel_launch(void* const* d_in, const int* in_sizes, int n_in,
                              void* d_out, int out_size, void* d_ws, size_t ws_size,
                              hipStream_t stream) {
    const int* X = (const int*)d_in[0];
    const int* Y = (const int*)d_in[1];
    const float* emb_src = (const float*)d_in[2];
    const float* emb_tgt = (const float*)d_in[3];
    const float* eWih = (const float*)d_in[4];
    const float* eWhh = (const float*)d_in[5];
    const float* ebih = (const float*)d_in[6];
    const float* ebhh = (const float*)d_in[7];
    const float* dWih = (const float*)d_in[8];
    const float* dWhh = (const float*)d_in[9];
    const float* dbih = (const float*)d_in[10];
    const float* dbhh = (const float*)d_in[11];
    const float* fcW = (const float*)d_in[12];
    const float* fcb = (const float*)d_in[13];
    float* out = (float*)d_out;

    // ws layout: [0,512KB) gen-quanta h buffers; [512KB,+1KB) barrier slots;
    //            [516KB,+256B) row_sums; [520KB,+8.192MB) fp32 logits
    unsigned* hq    = (unsigned*)d_ws;
    unsigned* bars  = (unsigned*)((char*)d_ws + 524288);
    float* row_sums = (float*)((char*)d_ws + 528384);
    float* logits   = (float*)((char*)d_ws + 532480);

    init_kernel<<<dim3(64), dim3(NT), 0, stream>>>(hq, row_sums, bars);

    void* args[] = {&X, &Y, &emb_src, &emb_tgt, &eWih, &eWhh, &ebih, &ebhh,
                    &dWih, &dWhh, &dbih, &dbhh, &hq, &bars};
    hipLaunchCooperativeKernel(reinterpret_cast<void*>(scan_kernel),
                               dim3(NB), dim3(NT), args, 0, stream);

    fc_kernel<<<dim3(VT / 128), dim3(NT), 0, stream>>>(fcW, fcb, hq, logits, row_sums);

    norm_kernel<<<dim3((Bz * VT) / NT), dim3(NT), 0, stream>>>(logits, row_sums, out);
}